// Round 2
// baseline (1138.214 us; speedup 1.0000x reference)
//
#include <hip/hip_runtime.h>
#include <math.h>

#define DIM   1024
#define NE    64
#define NQ    256
#define NCOL  320
#define BM    64
#define BK    32
#define NT    (DIM / BK)   // 32 k-tiles

// LDS tile layout (float4 slots, 16B each):
//   A region: slot = 9*ta + q   (ta=token 0..63, q=k-chunk 0..7; stride 9 pads banks)
//             region padded to 768 slots (3 staging issues x 256)
//   B region: slot = 161*c + 8*n + q  (c=col-group 0..15, n=0..19, q=0..7)
//             region padded to 2816 slots (11 staging issues x 256)
#define A_SLOTS 768
#define B_SLOTS 2816
#define A_BYTES (A_SLOTS * 16)              // 12288
#define LDS_BYTES (A_BYTES + B_SLOTS * 16)  // 57344

// global -> LDS direct (16B per lane, LDS dest = wave-uniform base + lane*16)
__device__ __forceinline__ void gload16(const void* gptr, void* lptr) {
  __builtin_amdgcn_global_load_lds(
      (const __attribute__((address_space(1))) unsigned int*)(unsigned long long)gptr,
      (__attribute__((address_space(3))) unsigned int*)(unsigned int)(unsigned long long)lptr,
      16, 0, 0);
}

__global__ __launch_bounds__(256, 2)
void ur_fused(const float* __restrict__ hs,    // [M,1024]
              const float* __restrict__ Wr,    // [64,1024]
              const float* __restrict__ br,    // [64]
              const float* __restrict__ Wu1,   // [256,1024]
              const float* __restrict__ bu1,   // [256]
              const float* __restrict__ Wu2,   // [256]
              const float* __restrict__ bu2,   // [1]
              float* __restrict__ out,         // w[4M] | idx[4M] | k[M]
              int M) {
  __shared__ __align__(16) char smem[LDS_BYTES];

  const int tid = threadIdx.x;
  const int m0 = blockIdx.x * BM;
  const int r = tid >> 4;   // 0..15 -> tokens 4r..4r+3
  const int c = tid & 15;   // 0..15 -> cols 20c..20c+19

  // ---- prologue: per-thread staging source pointers (k0-invariant decode) ----
  const float* gA[3];
#pragma unroll
  for (int l = 0; l < 3; ++l) {
    int i = l * 256 + tid;          // LDS slot this lane fills
    int ta = i / 9, q = i % 9;
    gA[l] = (ta < BM && q < 8) ? (hs + (size_t)(m0 + ta) * DIM + q * 4) : hs;
  }
  const float* gB[11];
#pragma unroll
  for (int l = 0; l < 11; ++l) {
    int i = l * 256 + tid;
    int cg = i / 161, rem = i % 161;
    const float* p = Wr;  // dummy
    if (cg < 16 && rem < 160) {
      int n = rem >> 3, q = rem & 7;
      int col = cg * 20 + n;
      p = (col < NE ? (Wr + (size_t)col * DIM) : (Wu1 + (size_t)(col - NE) * DIM)) + q * 4;
    }
    gB[l] = p;
  }
  const unsigned wbase = (tid & ~63u) * 16u;  // wave-uniform lane-0 byte offset

  float acc[4][20];
#pragma unroll
  for (int j = 0; j < 4; ++j)
#pragma unroll
    for (int n = 0; n < 20; ++n) acc[j][n] = 0.f;

  const char* Ab = smem + 576 * r;            // 9*(4r)*16
  const char* Bb = smem + A_BYTES + 2576 * c; // 161*c*16

  for (int t = 0; t < NT; ++t) {
    __syncthreads();  // prev tile's readers done before overwrite
#pragma unroll
    for (int l = 0; l < 3; ++l) {
      gload16(gA[l], smem + (l * 256u * 16u + wbase));
      gA[l] += BK;  // +128 B
    }
#pragma unroll
    for (int l = 0; l < 11; ++l) {
      gload16(gB[l], smem + A_BYTES + (l * 256u * 16u + wbase));
      gB[l] += BK;
    }
    __syncthreads();  // drains vmcnt(0): tile resident

#pragma unroll
    for (int q = 0; q < 8; ++q) {
      float4 av[4];
#pragma unroll
      for (int j = 0; j < 4; ++j)
        av[j] = *reinterpret_cast<const float4*>(Ab + j * 144 + q * 16);
#pragma unroll
      for (int n = 0; n < 20; ++n) {
        const float4 bv = *reinterpret_cast<const float4*>(Bb + n * 128 + q * 16);
#pragma unroll
        for (int j = 0; j < 4; ++j) {
          acc[j][n] = fmaf(av[j].x, bv.x, acc[j][n]);
          acc[j][n] = fmaf(av[j].y, bv.y, acc[j][n]);
          acc[j][n] = fmaf(av[j].z, bv.z, acc[j][n]);
          acc[j][n] = fmaf(av[j].w, bv.w, acc[j][n]);
        }
      }
    }
  }
  __syncthreads();  // tile buffer dead; overlay epilogue arrays

  // ---- epilogue overlay (padded strides to kill bank conflicts) ----
  float* Lg = reinterpret_cast<float*>(smem);                 // [64][65]
  float* Xp = reinterpret_cast<float*>(smem + 16640);         // [16][65]
  float* Xs = reinterpret_cast<float*>(smem + 16640 + 4160);  // [64]

  float xp[4] = {0.f, 0.f, 0.f, 0.f};
#pragma unroll
  for (int n = 0; n < 20; ++n) {
    int col = c * 20 + n;
    if (col < NE) {
      float bias = br[col];
#pragma unroll
      for (int j = 0; j < 4; ++j) Lg[(r * 4 + j) * 65 + col] = acc[j][n] + bias;
    } else {
      int qd = col - NE;
      float w2 = Wu2[qd];
      float b1 = bu1[qd];
#pragma unroll
      for (int j = 0; j < 4; ++j) {
        float h = acc[j][n] + b1;
        float g = 0.5f * h * (1.f + erff(h * 0.70710678118654752440f));
        xp[j] = fmaf(g, w2, xp[j]);
      }
    }
  }
#pragma unroll
  for (int j = 0; j < 4; ++j) Xp[c * 65 + r * 4 + j] = xp[j];
  __syncthreads();

  if (tid < BM) {
    float x = bu2[0];
#pragma unroll
    for (int cc = 0; cc < 16; ++cc) x += Xp[cc * 65 + tid];
    Xs[tid] = x;
  }
  __syncthreads();

  // ---- per-token top-4 + masked softmax: one wave per token ----
  const int wave = tid >> 6;
  const int lane = tid & 63;
  const size_t Moff_i = 4 * (size_t)M;
  const size_t Moff_k = 8 * (size_t)M;

  for (int t = wave; t < BM; t += 4) {
    float cur = Lg[t * 65 + lane];
    float topv[4];
    int topi[4];
#pragma unroll
    for (int s = 0; s < 4; ++s) {
      float mv = cur;
      int mi = lane;
#pragma unroll
      for (int off = 32; off >= 1; off >>= 1) {
        float ov = __shfl_xor(mv, off, 64);
        int oi = __shfl_xor(mi, off, 64);
        if (ov > mv || (ov == mv && oi < mi)) { mv = ov; mi = oi; }
      }
      topv[s] = mv;
      topi[s] = mi;
      if (lane == mi) cur = -INFINITY;  // stable: lowest index wins ties
    }
    if (lane == 0) {
      const int token = m0 + t;
      float x = Xs[t];
      float u = 1.f / (1.f + expf(-x));
      float kf = fmaf(3.f, u, 1.f);
      int kv = (int)rintf(kf);  // round-half-even == jnp.round
      kv = kv < 1 ? 1 : (kv > 4 ? 4 : kv);

      float w[4];
#pragma unroll
      for (int s = 0; s < 4; ++s) w[s] = (s < kv) ? topv[s] : 0.f;
      float mx = fmaxf(fmaxf(w[0], w[1]), fmaxf(w[2], w[3]));
      float e[4], sum = 0.f;
#pragma unroll
      for (int s = 0; s < 4; ++s) { e[s] = expf(w[s] - mx); sum += e[s]; }
      float inv = 1.f / sum;
#pragma unroll
      for (int s = 0; s < 4; ++s) {
        out[(size_t)token * 4 + s] = e[s] * inv;
        out[Moff_i + (size_t)token * 4 + s] = (s < kv) ? (float)topi[s] : -1.0f;
      }
      out[Moff_k + token] = (float)kv;
    }
  }
}

extern "C" void kernel_launch(void* const* d_in, const int* in_sizes, int n_in,
                              void* d_out, int out_size, void* d_ws, size_t ws_size,
                              hipStream_t stream) {
  (void)n_in; (void)d_ws; (void)ws_size; (void)out_size;
  const float* hs  = (const float*)d_in[0];
  const float* Wr  = (const float*)d_in[1];
  const float* br  = (const float*)d_in[2];
  const float* Wu1 = (const float*)d_in[3];
  const float* bu1 = (const float*)d_in[4];
  const float* Wu2 = (const float*)d_in[5];
  const float* bu2 = (const float*)d_in[6];
  float* out = (float*)d_out;

  const int M = in_sizes[0] / DIM;  // 32768
  dim3 grid(M / BM);                // 512
  dim3 block(256);
  hipLaunchKernelGGL(ur_fused, grid, block, 0, stream,
                     hs, Wr, br, Wu1, bu1, Wu2, bu2, out, M);
}

// Round 3
// 576.914 us; speedup vs baseline: 1.9729x; 1.9729x over previous
//
#include <hip/hip_runtime.h>
#include <math.h>

#define DIM   1024
#define NE    64
#define BM    64
#define BK    32
#define NT    32          // 1024 / 32 k-tiles
#define A_BYTES 8192      // 64 rows x 8 float4-slots
#define B_BYTES 40960     // 320 rows x 8 float4-slots
#define TILE_BYTES (A_BYTES + B_BYTES)   // 49152

// global -> LDS direct copy, 16 B per lane. LDS dest = wave-uniform base + lane*16.
__device__ __forceinline__ void gload16(const void* gptr, void* lptr) {
  __builtin_amdgcn_global_load_lds(
      (const __attribute__((address_space(1))) unsigned int*)(unsigned long long)gptr,
      (__attribute__((address_space(3))) unsigned int*)(unsigned int)(unsigned long long)lptr,
      16, 0, 0);
}

__global__ __launch_bounds__(256)
void ur_fused(const float* __restrict__ hs,    // [M,1024]
              const float* __restrict__ Wr,    // [64,1024]
              const float* __restrict__ br,    // [64]
              const float* __restrict__ Wu1,   // [256,1024]
              const float* __restrict__ bu1,   // [256]
              const float* __restrict__ Wu2,   // [256]
              const float* __restrict__ bu2,   // [1]
              float* __restrict__ out,         // w[4M] | idx[4M] | k[M]
              int M) {
  __shared__ __align__(16) char smem[2 * TILE_BYTES];   // 96 KB double buffer

  const int tid = threadIdx.x;
  const int m0 = blockIdx.x * BM;
  const int r = tid >> 4;   // 0..15 -> tokens 4r..4r+3
  const int c = tid & 15;   // 0..15 -> cols c, c+16, ..., c+304

  // ---- staging source offsets (32-bit, SGPR base + voffset form) ----
  // LDS slot = 8*row + qs (linear, written by global_load_lds in lane order).
  // Global k-chunk q = qs ^ swizzle(row) so reads can xor-address (T2/m173).
  unsigned ofsA[2];
#pragma unroll
  for (int l = 0; l < 2; ++l) {
    int slot = l * 256 + tid;
    int ta = slot >> 3, qs = slot & 7;
    int q = qs ^ ((ta >> 2) & 7);
    ofsA[l] = ((unsigned)(m0 + ta) << 12) + ((unsigned)q << 4);
  }
  unsigned ofsB[10];
#pragma unroll
  for (int l = 0; l < 10; ++l) {
    int slot = l * 256 + tid;
    int col = slot >> 3, qs = slot & 7;     // issues 0-1: col<64 (Wr), 2-9: Wu1
    int q = qs ^ (col & 7);
    int row = (l < 2) ? col : (col - NE);
    ofsB[l] = ((unsigned)row << 12) + ((unsigned)q << 4);
  }
  const unsigned wb = (unsigned)(tid & ~63) * 16u;  // wave-uniform LDS base part

  float acc[4][20];
#pragma unroll
  for (int j = 0; j < 4; ++j)
#pragma unroll
    for (int n = 0; n < 20; ++n) acc[j][n] = 0.f;

  const unsigned rb = (unsigned)(r & 7) << 4;
  const unsigned cb = (unsigned)(c & 7) << 4;

  auto stage = [&](int buf) {
    char* base = smem + buf * TILE_BYTES;
#pragma unroll
    for (int l = 0; l < 2; ++l) {
      gload16((const char*)hs + ofsA[l], base + l * 4096 + wb);
      ofsA[l] += BK * 4;
    }
#pragma unroll
    for (int l = 0; l < 2; ++l) {
      gload16((const char*)Wr + ofsB[l], base + A_BYTES + l * 4096 + wb);
      ofsB[l] += BK * 4;
    }
#pragma unroll
    for (int l = 2; l < 10; ++l) {
      gload16((const char*)Wu1 + ofsB[l], base + A_BYTES + l * 4096 + wb);
      ofsB[l] += BK * 4;
    }
  };

  auto compute = [&](int buf) {
    const char* Ab = smem + buf * TILE_BYTES + r * 512;
    const char* Bb = smem + buf * TILE_BYTES + A_BYTES + c * 128;
#pragma unroll
    for (int q = 0; q < 8; ++q) {
      const unsigned qx = (unsigned)q << 4;
      const char* pa = Ab + (rb ^ qx);
      float4 av[4];
#pragma unroll
      for (int j = 0; j < 4; ++j)
        av[j] = *reinterpret_cast<const float4*>(pa + j * 128);
      const char* pb = Bb + (cb ^ qx);
#pragma unroll
      for (int n = 0; n < 20; ++n) {
        const float4 bv = *reinterpret_cast<const float4*>(pb + n * 2048);
#pragma unroll
        for (int j = 0; j < 4; ++j) {
          acc[j][n] = fmaf(av[j].x, bv.x, acc[j][n]);
          acc[j][n] = fmaf(av[j].y, bv.y, acc[j][n]);
          acc[j][n] = fmaf(av[j].z, bv.z, acc[j][n]);
          acc[j][n] = fmaf(av[j].w, bv.w, acc[j][n]);
        }
      }
    }
  };

  // ---- double-buffered main loop: counted vmcnt, raw barriers ----
  stage(0);
#pragma unroll 1
  for (int t = 0; t < NT - 1; ++t) {
    stage((t + 1) & 1);                       // 12 loads stay in flight
    asm volatile("s_waitcnt vmcnt(12)" ::: "memory");  // tile t resident
    __builtin_amdgcn_s_barrier();
    compute(t & 1);
    asm volatile("" ::: "memory");
    __builtin_amdgcn_s_barrier();             // readers done before overwrite
  }
  asm volatile("s_waitcnt vmcnt(0)" ::: "memory");
  __builtin_amdgcn_s_barrier();
  compute((NT - 1) & 1);
  __syncthreads();                            // tile buffers dead; overlay epilogue

  // ---- epilogue: biases, GELU, uncertainty dot; overlay arrays in LDS ----
  float* Lg = reinterpret_cast<float*>(smem);                 // [64][65]
  float* Xp = reinterpret_cast<float*>(smem + 16640);         // [16][65]
  float* Xs = reinterpret_cast<float*>(smem + 16640 + 4160);  // [64]

  float xp[4] = {0.f, 0.f, 0.f, 0.f};
#pragma unroll
  for (int n = 0; n < 20; ++n) {
    int col = c + 16 * n;
    if (n < 4) {                 // router cols 0..63
      float bias = br[col];
#pragma unroll
      for (int j = 0; j < 4; ++j) Lg[(r * 4 + j) * 65 + col] = acc[j][n] + bias;
    } else {                     // u1 cols 64..319
      int qd = col - NE;
      float w2 = Wu2[qd];
      float b1 = bu1[qd];
#pragma unroll
      for (int j = 0; j < 4; ++j) {
        float h = acc[j][n] + b1;
        float g = 0.5f * h * (1.f + erff(h * 0.70710678118654752440f));
        xp[j] = fmaf(g, w2, xp[j]);
      }
    }
  }
#pragma unroll
  for (int j = 0; j < 4; ++j) Xp[c * 65 + r * 4 + j] = xp[j];
  __syncthreads();

  if (tid < BM) {
    float x = bu2[0];
#pragma unroll
    for (int cc = 0; cc < 16; ++cc) x += Xp[cc * 65 + tid];
    Xs[tid] = x;
  }
  __syncthreads();

  // ---- per-token top-4 + masked softmax: one wave per token ----
  const int wave = tid >> 6;
  const int lane = tid & 63;
  const size_t Moff_i = 4 * (size_t)M;
  const size_t Moff_k = 8 * (size_t)M;

  for (int t = wave; t < BM; t += 4) {
    float cur = Lg[t * 65 + lane];
    float topv[4];
    int topi[4];
#pragma unroll
    for (int s = 0; s < 4; ++s) {
      float mv = cur;
      int mi = lane;
#pragma unroll
      for (int off = 32; off >= 1; off >>= 1) {
        float ov = __shfl_xor(mv, off, 64);
        int oi = __shfl_xor(mi, off, 64);
        if (ov > mv || (ov == mv && oi < mi)) { mv = ov; mi = oi; }
      }
      topv[s] = mv;
      topi[s] = mi;
      if (lane == mi) cur = -INFINITY;  // stable: lowest index wins ties
    }
    if (lane == 0) {
      const int token = m0 + t;
      float x = Xs[t];
      float u = 1.f / (1.f + expf(-x));
      float kf = fmaf(3.f, u, 1.f);
      int kv = (int)rintf(kf);          // round-half-even == jnp.round
      kv = kv < 1 ? 1 : (kv > 4 ? 4 : kv);

      float w[4];
#pragma unroll
      for (int s = 0; s < 4; ++s) w[s] = (s < kv) ? topv[s] : 0.f;
      float mx = fmaxf(fmaxf(w[0], w[1]), fmaxf(w[2], w[3]));
      float e[4], sum = 0.f;
#pragma unroll
      for (int s = 0; s < 4; ++s) { e[s] = expf(w[s] - mx); sum += e[s]; }
      float inv = 1.f / sum;
#pragma unroll
      for (int s = 0; s < 4; ++s) {
        out[(size_t)token * 4 + s] = e[s] * inv;
        out[Moff_i + (size_t)token * 4 + s] = (s < kv) ? (float)topi[s] : -1.0f;
      }
      out[Moff_k + token] = (float)kv;
    }
  }
}

extern "C" void kernel_launch(void* const* d_in, const int* in_sizes, int n_in,
                              void* d_out, int out_size, void* d_ws, size_t ws_size,
                              hipStream_t stream) {
  (void)n_in; (void)d_ws; (void)ws_size; (void)out_size;
  const float* hs  = (const float*)d_in[0];
  const float* Wr  = (const float*)d_in[1];
  const float* br  = (const float*)d_in[2];
  const float* Wu1 = (const float*)d_in[3];
  const float* bu1 = (const float*)d_in[4];
  const float* Wu2 = (const float*)d_in[5];
  const float* bu2 = (const float*)d_in[6];
  float* out = (float*)d_out;

  const int M = in_sizes[0] / DIM;  // 32768
  dim3 grid(M / BM);                // 512 blocks, 1 resident/CU (96 KB LDS)
  dim3 block(256);
  hipLaunchKernelGGL(ur_fused, grid, block, 0, stream,
                     hs, Wr, br, Wu1, bu1, Wu2, bu2, out, M);
}